// Round 5
// baseline (494.107 us; speedup 1.0000x reference)
//
#include <hip/hip_runtime.h>
#include <hip/hip_bf16.h>
#include <stdint.h>

// HQQ grouped GEMM, MI355X (gfx950) — round 5.
//   y[t,o] = sum_g scale[e,g,o] * (x_g @ Wq_g)[t,o] - sum_g r[t,g]*zero*scale
// x split into bf16 hi+lo planes; Wq exact in bf16; zero-term folded as
// pseudo K-group 16 (A cols [r_hi|r_hi|r_lo|0], B rows [-zs_hi|-zs_lo|-zs_hi|0]).
//
// Round-5 (round 4 NaN'd): the ks=1 B-read used broff^32 to get "granule+4",
// but XOR on the full offset (nrow*72 + granule*8) corrupts when low bits
// carry -> reads walked out of the LDS buffer (NaN via MFMA). Fix: explicit
// broff1 with granule ((gk+4+(nrow>>2))&7) — carry-free.
// Also: A double-buffered in registers (BODY(g) issues A(g+1)+B(g+2),
// computes on resident A(g)) -> no VMEM wait ever blocks the MFMA phase;
// barrier stays lgkm-only so in-flight loads cross it (T4 effect).

namespace {
constexpr int kE = 8;
constexpr int kIn = 1024;
constexpr int kOut = 2816;
constexpr int kGroups = 16;         // quant groups along IN (GS=64)
constexpr int kTok = 2048;
constexpr int kXStride = kIn + 64;  // 1088: x cols + pseudo-group cols
constexpr int kBM = 64;
constexpr int kBN = 128;
constexpr int kBTS = 72;            // Bt LDS row stride in elems (144B)
constexpr int kNT = kOut / kBN;     // 22 n-tiles
constexpr int kGrid = kNT * 256;    // 5632 = 8 * 704
}

typedef __attribute__((ext_vector_type(8))) short short8;
typedef __attribute__((ext_vector_type(4))) float f32x4;
typedef __attribute__((ext_vector_type(4))) int i32x4;
typedef __attribute__((ext_vector_type(4))) unsigned int u32x4;

struct AFrag { short8 h0[2], l0[2], h1[2], l1[2]; };  // 32 VGPRs

static __device__ __forceinline__ uint32_t fbits(float f) {
  union { float f; uint32_t u; } v; v.f = f; return v.u;
}
static __device__ __forceinline__ unsigned short bf16_rne(float f) {
  uint32_t u = fbits(f);
  u += 0x7fffu + ((u >> 16) & 1u);
  return (unsigned short)(u >> 16);
}
static __device__ __forceinline__ float bf16_f(unsigned short h) {
  union { uint32_t u; float f; } v; v.u = ((uint32_t)h) << 16; return v.f;
}
static __device__ __forceinline__ u32x4 pack8(const unsigned short* u) {
  u32x4 r;
#pragma unroll
  for (int ww = 0; ww < 4; ++ww)
    r[ww] = (uint32_t)u[2 * ww] | ((uint32_t)u[2 * ww + 1] << 16);
  return r;
}

// ---------------- prep: x -> bf16 hi/lo planes + group rowsums ----------------
__global__ __launch_bounds__(256) void hqq_prep(const float* __restrict__ x,
                                                unsigned short* __restrict__ xhi,
                                                unsigned short* __restrict__ xlo) {
  const int row = blockIdx.x;
  const int tid = threadIdx.x;
  const f32x4 v = *(const f32x4*)(x + (size_t)row * kIn + tid * 4);
  unsigned long long hp = 0, lp = 0;
  float s = 0.f;
#pragma unroll
  for (int j = 0; j < 4; ++j) {
    float f = v[j];
    unsigned short h = bf16_rne(f);
    unsigned short l = bf16_rne(f - bf16_f(h));
    hp |= ((unsigned long long)h) << (16 * j);
    lp |= ((unsigned long long)l) << (16 * j);
    s += f;
  }
  *(unsigned long long*)(xhi + (size_t)row * kXStride + tid * 4) = hp;
  *(unsigned long long*)(xlo + (size_t)row * kXStride + tid * 4) = lp;
#pragma unroll
  for (int m = 1; m <= 8; m <<= 1) s += __shfl_xor(s, m, 64);
  if ((tid & 15) == 0) {
    const int g = tid >> 4;
    unsigned short rhi = bf16_rne(s);
    unsigned short rlo = bf16_rne(s - bf16_f(rhi));
    unsigned short* p = xhi + (size_t)row * kXStride + kIn;
    p[g] = rhi; p[16 + g] = rhi; p[32 + g] = rlo; p[48 + g] = 0;
    unsigned short* q = xlo + (size_t)row * kXStride + kIn;
    q[g] = 0; q[16 + g] = 0; q[32 + g] = 0; q[48 + g] = 0;
  }
}

// ---------------- grouped GEMM ----------------

// A fragment loads for K-group g1 (8x 16B per thread, coalesced 64B rows).
#define ALOAD(g1, AF)                                                   \
  {                                                                     \
    _Pragma("unroll")                                                   \
    for (int mf_ = 0; mf_ < 2; ++mf_) {                                 \
      AF.h0[mf_] = *(const short8*)&xhi[arow[mf_] + (g1) * 64 + klane]; \
      AF.l0[mf_] = *(const short8*)&xlo[arow[mf_] + (g1) * 64 + klane]; \
      AF.h1[mf_] = *(const short8*)&xhi[arow[mf_] + (g1) * 64 + 32 + klane]; \
      AF.l1[mf_] = *(const short8*)&xlo[arow[mf_] + (g1) * 64 + 32 + klane]; \
    }                                                                   \
  }

// B global load: 8x dwordx4, coalesced (32 lanes x 16B per k-row).
#define LOADB(g, W)                                                     \
  {                                                                     \
    const int* p_ = wbase + (size_t)(g) * 64 * kOut;                    \
    _Pragma("unroll")                                                   \
    for (int i_ = 0; i_ < 8; ++i_) W[i_] = *(const i32x4*)(p_ + (size_t)i_ * kOut); \
  }

// B cvt + transposed LDS write, bank-rotated granule (kc+oq)&7.
#define WRITEB(buf, W)                                                  \
  {                                                                     \
    unsigned short* btw_ = &Bt[buf][(oq * 4) * kBTS + (((kc + oq) & 7) * 8)]; \
    _Pragma("unroll")                                                   \
    for (int j_ = 0; j_ < 4; ++j_) {                                    \
      u32x4 o_;                                                         \
      _Pragma("unroll")                                                 \
      for (int ww_ = 0; ww_ < 4; ++ww_) {                               \
        uint32_t b0_ = fbits((float)W[2 * ww_][j_]);                    \
        uint32_t b1_ = fbits((float)W[2 * ww_ + 1][j_]);                \
        o_[ww_] = (b0_ >> 16) | (b1_ & 0xffff0000u);                    \
      }                                                                 \
      *(u32x4*)(btw_ + j_ * kBTS) = o_;                                 \
    }                                                                   \
  }

#define ZSLOAD()                                                        \
  {                                                                     \
    _Pragma("unroll")                                                   \
    for (int gg_ = 0; gg_ < 16; ++gg_) {                                \
      zv[gg_] = zrow[(size_t)gg_ * kOut];                               \
      sv[gg_] = srow[(size_t)gg_ * kOut];                               \
    }                                                                   \
  }

// pseudo group 16: B rows [-zs_hi | -zs_lo | -zs_hi | 0] into Bt[0],
// same granule rotation as WRITEB.
#define PSEUDOWRITE()                                                   \
  {                                                                     \
    unsigned short zh_[16], zl_[16];                                    \
    _Pragma("unroll")                                                   \
    for (int gg_ = 0; gg_ < 16; ++gg_) {                                \
      float zs_ = -(zv[gg_] * sv[gg_]);                                 \
      unsigned short hh_ = bf16_rne(zs_);                               \
      zh_[gg_] = hh_; zl_[gg_] = bf16_rne(zs_ - bf16_f(hh_));           \
    }                                                                   \
    unsigned short* wrow_ = &Bt[0][o_ps * kBTS];                        \
    const int rq_ = (o_ps >> 2) & 7;                                    \
    if (h_ps == 0) {                                                    \
      *(u32x4*)(wrow_ + (((0 + rq_) & 7) * 8)) = pack8(zh_);            \
      *(u32x4*)(wrow_ + (((1 + rq_) & 7) * 8)) = pack8(zh_ + 8);        \
      *(u32x4*)(wrow_ + (((2 + rq_) & 7) * 8)) = pack8(zl_);            \
      *(u32x4*)(wrow_ + (((3 + rq_) & 7) * 8)) = pack8(zl_ + 8);        \
    } else {                                                            \
      u32x4 zz_; zz_[0] = zz_[1] = zz_[2] = zz_[3] = 0;                 \
      *(u32x4*)(wrow_ + (((4 + rq_) & 7) * 8)) = pack8(zh_);            \
      *(u32x4*)(wrow_ + (((5 + rq_) & 7) * 8)) = pack8(zh_ + 8);        \
      *(u32x4*)(wrow_ + (((6 + rq_) & 7) * 8)) = zz_;                   \
      *(u32x4*)(wrow_ + (((7 + rq_) & 7) * 8)) = zz_;                   \
    }                                                                   \
  }

// MFMA phase on Bt[g&1] using resident A-frags AS.
#define MFMA_PHASE(g, AS)                                               \
  {                                                                     \
    f32x4 S[2][4];                                                      \
    _Pragma("unroll")                                                   \
    for (int a_ = 0; a_ < 2; ++a_)                                      \
      _Pragma("unroll")                                                 \
      for (int b_ = 0; b_ < 4; ++b_) S[a_][b_] = 0.f;                   \
    const unsigned short* btb_ = &Bt[(g) & 1][0];                       \
    {                                                                   \
      short8 bb[4];                                                     \
      _Pragma("unroll")                                                 \
      for (int nf_ = 0; nf_ < 4; ++nf_)                                 \
        bb[nf_] = *(const short8*)&btb_[broff0[nf_]];                   \
      _Pragma("unroll")                                                 \
      for (int mf_ = 0; mf_ < 2; ++mf_)                                 \
        _Pragma("unroll")                                               \
        for (int nf_ = 0; nf_ < 4; ++nf_) {                             \
          S[mf_][nf_] = __builtin_amdgcn_mfma_f32_16x16x32_bf16(AS.h0[mf_], bb[nf_], S[mf_][nf_], 0, 0, 0); \
          S[mf_][nf_] = __builtin_amdgcn_mfma_f32_16x16x32_bf16(AS.l0[mf_], bb[nf_], S[mf_][nf_], 0, 0, 0); \
        }                                                               \
    }                                                                   \
    {                                                                   \
      short8 bb[4];                                                     \
      _Pragma("unroll")                                                 \
      for (int nf_ = 0; nf_ < 4; ++nf_)                                 \
        bb[nf_] = *(const short8*)&btb_[broff1[nf_]];                   \
      _Pragma("unroll")                                                 \
      for (int mf_ = 0; mf_ < 2; ++mf_)                                 \
        _Pragma("unroll")                                               \
        for (int nf_ = 0; nf_ < 4; ++nf_) {                             \
          S[mf_][nf_] = __builtin_amdgcn_mfma_f32_16x16x32_bf16(AS.h1[mf_], bb[nf_], S[mf_][nf_], 0, 0, 0); \
          S[mf_][nf_] = __builtin_amdgcn_mfma_f32_16x16x32_bf16(AS.l1[mf_], bb[nf_], S[mf_][nf_], 0, 0, 0); \
        }                                                               \
    }                                                                   \
    _Pragma("unroll")                                                   \
    for (int mf_ = 0; mf_ < 2; ++mf_)                                   \
      _Pragma("unroll")                                                 \
      for (int nf_ = 0; nf_ < 4; ++nf_) acc[mf_][nf_] += sc_cur[nf_] * S[mf_][nf_]; \
  }

// One pipeline iteration: issue A(g+1), B(g+2); compute on A(g), Bt[g&1];
// stage B(g+1) to LDS; lgkm-only barrier (VMEM stays in flight across it).
#define BODY(g, AFILL, ASPEND, WFILL, WSPEND)                           \
  {                                                                     \
    ALOAD((g) + 1, AFILL);                                              \
    __builtin_amdgcn_sched_barrier(0);                                  \
    if ((g) <= 13) {                                                    \
      LOADB((g) + 2, WFILL);                                            \
    } else if ((g) == 14) {                                             \
      ZSLOAD();                                                         \
    }                                                                   \
    if ((g) <= 14) {                                                    \
      _Pragma("unroll")                                                 \
      for (int nf_ = 0; nf_ < 4; ++nf_)                                 \
        sc_nxt[nf_] = sc_base[(size_t)((g) + 1) * kOut + nf_ * 16];     \
    } else {                                                            \
      _Pragma("unroll")                                                 \
      for (int nf_ = 0; nf_ < 4; ++nf_) sc_nxt[nf_] = 1.f;              \
    }                                                                   \
    __builtin_amdgcn_sched_barrier(0);                                  \
    MFMA_PHASE(g, ASPEND);                                              \
    _Pragma("unroll")                                                   \
    for (int nf_ = 0; nf_ < 4; ++nf_) sc_cur[nf_] = sc_nxt[nf_];        \
    if ((g) <= 14) {                                                    \
      WRITEB(((g) + 1) & 1, WSPEND);                                    \
    } else {                                                            \
      PSEUDOWRITE();                                                    \
    }                                                                   \
    asm volatile("s_waitcnt lgkmcnt(0)\n\ts_barrier" ::: "memory");     \
  }

__global__ __launch_bounds__(256, 2) void hqq_gemm(
    const unsigned short* __restrict__ xhi, const unsigned short* __restrict__ xlo,
    const int* __restrict__ wq, const float* __restrict__ scales,
    const float* __restrict__ zeros, const int* __restrict__ tpe,
    float* __restrict__ out) {
  __shared__ unsigned short Bt[2][kBN * kBTS];  // 2 x 18 KB

  // T1 XCD swizzle (5632 = 8*704): a panel's m-tiles share one XCD L2.
  const int raw = blockIdx.x;
  const int bid = (raw & 7) * (kGrid / 8) + (raw >> 3);

  const int nt = bid >> 8;
  const int em = bid & 255;
  const int e = em >> 5;
  const int mt = em & 31;

  int e_start = 0, cnt = 0, cum = 0;
#pragma unroll
  for (int i = 0; i < kE; ++i) {
    int c = tpe[i];
    if (i == e) { e_start = cum; cnt = c; }
    cum += c;
  }
  if (mt * kBM >= cnt) return;  // block-uniform exit (before any barrier)
  const int e_end = e_start + cnt;
  const int row0 = e_start + mt * kBM;
  const int nn = nt * kBN;

  const int tid = threadIdx.x;
  const int lane = tid & 63;
  const int wid = tid >> 6;
  const int wm = wid >> 1;
  const int wn = wid & 1;

  // A fragment row bases (clamped)
  size_t arow[2];
#pragma unroll
  for (int mf = 0; mf < 2; ++mf) {
    int r = row0 + wm * 32 + mf * 16 + (lane & 15);
    if (r > kTok - 1) r = kTok - 1;
    arow[mf] = (size_t)r * kXStride;
  }
  const int klane = (lane >> 4) * 8;  // A k-offset within a 32-col half

  // B read offsets, granule-rotated: row nrow, k-chunk c stored at granule
  // (c + (nrow>>2)) & 7.  ks=0 -> c = gk (0..3); ks=1 -> c = gk+4.
  int broff0[4], broff1[4];
#pragma unroll
  for (int nf = 0; nf < 4; ++nf) {
    const int nrow = wn * 64 + nf * 16 + (lane & 15);
    const int gk = lane >> 4;  // 0..3
    broff0[nf] = nrow * kBTS + (((gk + (nrow >> 2)) & 7) * 8);
    broff1[nf] = nrow * kBTS + (((gk + 4 + (nrow >> 2)) & 7) * 8);
  }

  // B staging thread mapping: 8k x 4o per thread
  const int oq = tid & 31;
  const int kc = tid >> 5;
  const int* wbase = wq + (size_t)e * kIn * kOut + (size_t)(kc * 8) * kOut + nn + oq * 4;

  const float* sc_base = scales + (size_t)e * kGroups * kOut + nn + wn * 64 + (lane & 15);

  // pseudo-group staging mapping
  const int o_ps = tid >> 1;
  const int h_ps = tid & 1;
  const float* zrow = zeros + (size_t)e * kGroups * kOut + nn + o_ps;
  const float* srow = scales + (size_t)e * kGroups * kOut + nn + o_ps;

  i32x4 wA[8], wB[8];
  AFrag aA, aB;
  float zv[16], sv[16];
  float sc_cur[4], sc_nxt[4];
  f32x4 acc[2][4];
#pragma unroll
  for (int a = 0; a < 2; ++a)
#pragma unroll
    for (int b = 0; b < 4; ++b) acc[a][b] = 0.f;

  // ---- prologue: Bt[0]=B(0); wB=B(1) and aA=A(0) in flight ----
  LOADB(0, wB);
  WRITEB(0, wB);
  LOADB(1, wB);
  ALOAD(0, aA);
#pragma unroll
  for (int nf = 0; nf < 4; ++nf) sc_cur[nf] = sc_base[nf * 16];
  asm volatile("s_waitcnt lgkmcnt(0)\n\ts_barrier" ::: "memory");

  // ---- main loop: 16 real groups, A depth-1 + B depth-2 pipelined ----
  for (int gg = 0; gg < 16; gg += 2) {
    BODY(gg, aB, aA, wA, wB);
    BODY(gg + 1, aA, aB, wB, wA);
  }

  // ---- iter 16: pseudo group (A(16) resident in aA, Bt[0] staged) ----
  MFMA_PHASE(0, aA);

  // ---- epilogue: predicated fp32 stores ----
  float* ob = out + nn + wn * 64 + (lane & 15);
#pragma unroll
  for (int mf = 0; mf < 2; ++mf)
#pragma unroll
    for (int i = 0; i < 4; ++i) {
      const int t = row0 + wm * 32 + mf * 16 + (lane >> 4) * 4 + i;
      if (t < e_end) {
#pragma unroll
        for (int nf = 0; nf < 4; ++nf)
          ob[(size_t)t * kOut + nf * 16] = acc[mf][nf][i];
      }
    }
}

extern "C" void kernel_launch(void* const* d_in, const int* in_sizes, int n_in,
                              void* d_out, int out_size, void* d_ws, size_t ws_size,
                              hipStream_t stream) {
  const float* x = (const float*)d_in[0];
  const int* tpe = (const int*)d_in[1];
  const int* wq = (const int*)d_in[2];
  const float* scales = (const float*)d_in[3];
  const float* zeros = (const float*)d_in[4];
  float* out = (float*)d_out;

  unsigned short* xhi = (unsigned short*)d_ws;
  unsigned short* xlo = xhi + (size_t)kTok * kXStride;

  hqq_prep<<<dim3(kTok), dim3(256), 0, stream>>>(x, xhi, xlo);
  hqq_gemm<<<dim3(kGrid), dim3(256), 0, stream>>>(xhi, xlo, wq, scales, zeros, tpe, out);
}